// Round 1
// baseline (215.407 us; speedup 1.0000x reference)
//
#include <hip/hip_runtime.h>
#include <stdint.h>

// Problem constants (from reference): B=16384, F=32, D=64, H=2*D=128.
#define B_SZ 16384
#define F_SZ 32
#define D_SZ 64
#define H_SZ 128
#define RSTRIDE 72   // w1l LDS row stride in shorts (144 B) -> conflict-free A-frag reads

typedef __attribute__((ext_vector_type(8))) short  short8;   // 8 x bf16 MFMA frag
typedef __attribute__((ext_vector_type(4))) float  float4v;
typedef __attribute__((ext_vector_type(4))) unsigned int uint4v;

// round-half-up f32->bf16, pack (lo -> bits[15:0], hi -> bits[31:16])
__device__ __forceinline__ unsigned int pkbf(float lo, float hi) {
  unsigned int ulo = __builtin_bit_cast(unsigned int, lo) + 0x8000u;
  unsigned int uhi = __builtin_bit_cast(unsigned int, hi) + 0x8000u;
  return __builtin_amdgcn_perm(uhi, ulo, 0x07060302u);
}

// Single fused kernel: zero workspace usage (diagnostic for the 512 MiB
// per-iteration ws re-poison fills that dominate the rocprof top-5), zero
// extra launches, direct interleaved (X, y) float2 output.
//
// Grid = 1024 blocks = 32 f (outer) x 32 row-tiles (inner). Tile-major inner
// means bid % 8 == tile % 8, so all 32 f-blocks of one row-tile share an XCD:
// the scattered per-f out/X accesses coalesce in that XCD's L2.
//
// Per block:
//   1. Inline weight prep: W1[f] (f32 [D][H]) -> LDS transpose -> bf16 w1l
//      in A-fragment order [h][d] (RSTRIDE-padded). Same round-half-up
//      conversion as the old prep kernel -> identical numerics.
//      {b1,w2} packed per h into bwl (b1 hi16, w2 lo16).
//   2. Tuned main loop (unchanged): 4 waves x 128 rows, 8 subtiles of 16 rows;
//      r_ staged via global_load_lds width=16 into per-wave 4 KB chunk-major
//      LDS (zero staging VGPRs, conflict-free frag reads), 16 MFMA/subtile.
//   3. Epilogue: quad==0 lanes write float2 {X[row][f], y} to out[row][2f].
__global__ __launch_bounds__(256) void ContMlp_fused(
    const float* __restrict__ X, const float* __restrict__ r_,
    const float* __restrict__ W1, const float* __restrict__ b1,
    const float* __restrict__ W2, const float* __restrict__ b2,
    float* __restrict__ out) {
  const int f    = blockIdx.x >> 5;
  const int tile = blockIdx.x & 31;
  const int w    = threadIdx.x >> 6;
  const int l    = threadIdx.x & 63;
  const int col  = l & 15;
  const int quad = l >> 4;

  __shared__ unsigned short w1l[H_SZ * RSTRIDE];   // 18432 B
  __shared__ unsigned int   bwl[H_SZ];             // 512 B
  __shared__ float          rbuf[4][1024];         // 16384 B, 4 KB per wave
  // total 35.3 KB -> 4 blocks/CU (VGPR budget 128)

  {  // ---- inline weight prep (once per block; W1[f] is L2-resident) ----
    const float* w1f = W1 + (size_t)f * (D_SZ * H_SZ);
    // f32 transpose temp aliased over rbuf (8448 B), dead before main loop
    float (*tmp)[33] = (float (*)[33])&rbuf[0][0];
    for (int hq = 0; hq < 4; ++hq) {
      const int h0 = hq * 32;
      __syncthreads();   // protect tmp reuse across hq iterations
#pragma unroll
      for (int i = 0; i < 8; ++i) {
        int idx = threadIdx.x + 256 * i;
        int d = idx >> 5, hh = idx & 31;
        tmp[d][hh] = w1f[d * H_SZ + h0 + hh];   // coalesced 128B/32 lanes
      }
      __syncthreads();
#pragma unroll
      for (int i = 0; i < 4; ++i) {
        int idx = threadIdx.x + 256 * i;
        int hh = idx & 31, dp = idx >> 5;       // d-pair 0..31
        unsigned int v = pkbf(tmp[2 * dp][hh], tmp[2 * dp + 1][hh]);
        *(unsigned int*)(w1l + (h0 + hh) * RSTRIDE + 2 * dp) = v;
      }
    }
    if (threadIdx.x < H_SZ) {
      unsigned int ub = __builtin_bit_cast(unsigned int, b1[f * H_SZ + threadIdx.x]) + 0x8000u;
      unsigned int uw = __builtin_bit_cast(unsigned int, W2[f * H_SZ + threadIdx.x]) + 0x8000u;
      bwl[threadIdx.x] = (ub & 0xFFFF0000u) | (uw >> 16);
    }
    __syncthreads();
  }
  const float b2f = b2[f];

  const int row_w0 = tile * 512 + w * 128;
  // lane's staging gather base: row (row_w0 + col), float offset quad*4
  const float* gl = r_ + (size_t)(row_w0 + col) * (F_SZ * D_SZ)
                       + f * D_SZ + quad * 4;
  float* rb = &rbuf[w][0];
  float yv[8];

#pragma unroll 1
  for (int s = 0; s < 8; ++s) {
    const float* gs = gl + (size_t)s * 16 * (F_SZ * D_SZ);
#pragma unroll
    for (int i = 0; i < 4; ++i) {
      __builtin_amdgcn_global_load_lds(
          (const __attribute__((address_space(1))) void*)(gs + i * 16),
          (__attribute__((address_space(3))) void*)(rb + i * 256),
          16, 0, 0);
    }
    __builtin_amdgcn_s_waitcnt(0x0F70);   // vmcnt(0), lgkm/exp untouched

    // fragment read (chunk-major): chunk c lives at floats (c*16+col)*4
    float4v f0 = *(const float4v*)(rb + (quad * 2) * 64 + col * 4);
    float4v f1 = *(const float4v*)(rb + (quad * 2 + 1) * 64 + col * 4);
    float4v f2 = *(const float4v*)(rb + (8 + quad * 2) * 64 + col * 4);
    float4v f3 = *(const float4v*)(rb + (9 + quad * 2) * 64 + col * 4);
    uint4v bq0 = {pkbf(f0.x, f0.y), pkbf(f0.z, f0.w),
                  pkbf(f1.x, f1.y), pkbf(f1.z, f1.w)};
    uint4v bq1 = {pkbf(f2.x, f2.y), pkbf(f2.z, f2.w),
                  pkbf(f3.x, f3.y), pkbf(f3.z, f3.w)};
    short8 bf0 = __builtin_bit_cast(short8, bq0);
    short8 bf1 = __builtin_bit_cast(short8, bq1);

    float ysum = 0.f;
#pragma unroll
    for (int t = 0; t < 8; ++t) {
      const unsigned short* wrow = w1l + (col + 16 * t) * RSTRIDE + quad * 8;
      short8 a0 = *(const short8*)(wrow);
      short8 a1 = *(const short8*)(wrow + 32);
      float4v acc = {0.f, 0.f, 0.f, 0.f};
      acc = __builtin_amdgcn_mfma_f32_16x16x32_bf16(a0, bf0, acc, 0, 0, 0);
      acc = __builtin_amdgcn_mfma_f32_16x16x32_bf16(a1, bf1, acc, 0, 0, 0);
      uint4v bwv = *(const uint4v*)(bwl + 16 * t + quad * 4);
#pragma unroll
      for (int r = 0; r < 4; ++r) {
        unsigned int u = bwv[r];
        float b1v = __builtin_bit_cast(float, u & 0xFFFF0000u);
        float w2v = __builtin_bit_cast(float, u << 16);
        ysum = fmaf(fmaxf(acc[r] + b1v, 0.f), w2v, ysum);
      }
    }
    ysum += __shfl_xor(ysum, 16, 64);
    ysum += __shfl_xor(ysum, 32, 64);
    yv[s] = fmaxf(ysum + b2f, 0.f);
  }

  // ---- epilogue: interleaved (x, y) writes; same-tile blocks share an XCD,
  // so the 8B-scatter coalesces to full lines in that XCD's L2. ----
  if (quad == 0) {
#pragma unroll
    for (int s = 0; s < 8; ++s) {
      int row = row_w0 + s * 16 + col;
      float xv = X[(size_t)row * F_SZ + f];
      *(float2*)(out + (size_t)row * (2 * F_SZ) + 2 * f) = make_float2(xv, yv[s]);
    }
  }
}

extern "C" void kernel_launch(void* const* d_in, const int* in_sizes, int n_in,
                              void* d_out, int out_size, void* d_ws, size_t ws_size,
                              hipStream_t stream) {
  const float* X  = (const float*)d_in[0];
  const float* r_ = (const float*)d_in[1];
  const float* W1 = (const float*)d_in[2];
  const float* b1 = (const float*)d_in[3];
  const float* W2 = (const float*)d_in[4];
  const float* b2 = (const float*)d_in[5];
  float* out = (float*)d_out;
  (void)d_ws; (void)ws_size;   // zero workspace usage

  ContMlp_fused<<<F_SZ * 32, 256, 0, stream>>>(X, r_, W1, b1, W2, b2, out);
}